// Round 1
// baseline (363.226 us; speedup 1.0000x reference)
//
#include <hip/hip_runtime.h>
#include <math.h>

// Shapes (fixed by the reference setup_inputs)
#define NB   8192
#define NR   64
#define NM   64
#define NOUT 4096

// Workspace layout (bytes)
static constexpr size_t OFF_Q0 = 256;                          // 64*64 f32 = 16KB
static constexpr size_t OFF_Q1 = OFF_Q0 + 64 * 64 * 4;         // 16KB
static constexpr size_t OFF_Q2 = OFF_Q1 + 64 * 64 * 4;         // 4096*64 f32 = 1MB
static constexpr size_t OFF_T  = OFF_Q2 + (size_t)NOUT * NR * 4; // 8192*64 f32 = 2MB
// total ~3.2MB

__device__ __forceinline__ float wave_max(float v) {
#pragma unroll
  for (int off = 32; off > 0; off >>= 1)
    v = fmaxf(v, __shfl_down(v, off));
  return v;
}

// ---------------------------------------------------------------------------
// Kernel 1: absmax of the three factor tensors.
// slots[0]=|f0|max, slots[1]=|f1|max, slots[2]=|f2|max (float bits in uint).
// grid: 1024 blocks x 256 threads covers f2 (262144 elems) exactly; first 16
// blocks also cover f0/f1 (4096 elems each).
// ---------------------------------------------------------------------------
__global__ __launch_bounds__(256) void absmax_factors(
    const float* __restrict__ f0, const float* __restrict__ f1,
    const float* __restrict__ f2, unsigned* __restrict__ slots) {
  int idx = blockIdx.x * 256 + threadIdx.x;
  float a2 = fabsf(f2[idx]);
  a2 = wave_max(a2);
  if ((threadIdx.x & 63) == 0)
    atomicMax(&slots[2], __float_as_uint(a2));
  if (blockIdx.x < 16) {  // idx < 4096 for whole block
    float a0 = fabsf(f0[idx]);
    float a1 = fabsf(f1[idx]);
    a0 = wave_max(a0);
    a1 = wave_max(a1);
    if ((threadIdx.x & 63) == 0) {
      atomicMax(&slots[0], __float_as_uint(a0));
      atomicMax(&slots[1], __float_as_uint(a1));
    }
  }
}

__device__ __forceinline__ float fq_scale(unsigned bits) {
  return fmaxf(__uint_as_float(bits) * (1.0f / 127.0f), 1e-8f);
}

__device__ __forceinline__ float fq_apply(float x, float s) {
  // round-half-even like jnp.round / np.round
  float q = fminf(fmaxf(rintf(x / s), -128.0f), 127.0f);
  return q * s;
}

// ---------------------------------------------------------------------------
// Kernel 2: quantize factors into workspace.
// ---------------------------------------------------------------------------
__global__ __launch_bounds__(256) void quant_factors(
    const float* __restrict__ f0, const float* __restrict__ f1,
    const float* __restrict__ f2, const unsigned* __restrict__ slots,
    float* __restrict__ q0, float* __restrict__ q1, float* __restrict__ q2) {
  int idx = blockIdx.x * 256 + threadIdx.x;
  float s2 = fq_scale(slots[2]);
  q2[idx] = fq_apply(f2[idx], s2);
  if (blockIdx.x < 16) {
    float s0 = fq_scale(slots[0]);
    float s1 = fq_scale(slots[1]);
    q0[idx] = fq_apply(f0[idx], s0);
    q1[idx] = fq_apply(f1[idx], s1);
  }
}

// ---------------------------------------------------------------------------
// Kernel 3: T[b][r] = (x0[b,:] . q0[:,r]) * (x1[b,:] . q1[:,r])
// 16 b-rows per block; q0,q1 (+x row tiles) staged in LDS.
// ---------------------------------------------------------------------------
__global__ __launch_bounds__(256) void stage1(
    const float* __restrict__ x0, const float* __restrict__ x1,
    const float* __restrict__ q0, const float* __restrict__ q1,
    float* __restrict__ T) {
  __shared__ float q0s[64 * 64];
  __shared__ float q1s[64 * 64];
  __shared__ float x0s[16 * 64];
  __shared__ float x1s[16 * 64];
  int tid = threadIdx.x;
  int b0 = blockIdx.x * 16;

#pragma unroll
  for (int i = 0; i < 4; ++i) {
    int f = tid + i * 256;
    ((float4*)q0s)[f] = ((const float4*)q0)[f];
    ((float4*)q1s)[f] = ((const float4*)q1)[f];
  }
  ((float4*)x0s)[tid] = ((const float4*)(x0 + (size_t)b0 * 64))[tid];
  ((float4*)x1s)[tid] = ((const float4*)(x1 + (size_t)b0 * 64))[tid];
  __syncthreads();

  int r = tid & 63;
  int ty = tid >> 6;  // 0..3
#pragma unroll
  for (int bi = 0; bi < 4; ++bi) {
    int bl = ty * 4 + bi;
    float a0 = 0.0f, a1 = 0.0f;
#pragma unroll
    for (int k = 0; k < 64; ++k) {
      a0 += x0s[bl * 64 + k] * q0s[k * 64 + r];
      a1 += x1s[bl * 64 + k] * q1s[k * 64 + r];
    }
    T[(size_t)(b0 + bl) * 64 + r] = a0 * a1;
  }
}

// ---------------------------------------------------------------------------
// Kernel 4/5: stage2 — Y = T @ q2^T (+bias).
// MODE 0: reduce absmax(|Y+bias|) into slots[3] (as float bits).
// MODE 1: out = relu(fake_quant(Y+bias)) with scale from slots[3].
// 64x64 output tile per block, K=64 (whole R). LDS holds transposed tiles
// Tt[k][b], Qt[k][o] so the inner loop is two ds_read_b128 + 16 FMA per k.
// ---------------------------------------------------------------------------
template <int MODE>
__global__ __launch_bounds__(256) void stage2(
    const float* __restrict__ T, const float* __restrict__ q2,
    const float* __restrict__ bias, unsigned* __restrict__ absmaxY,
    float* __restrict__ out) {
  __shared__ float Tt[64 * 64];  // [k][b]
  __shared__ float Qt[64 * 64];  // [k][o]
  __shared__ float wred[4];

  int tid = threadIdx.x;
  int ot = blockIdx.x;  // 0..63   (OUT tiles)
  int bt = blockIdx.y;  // 0..127  (B tiles)

  const float* Tg = T + (size_t)bt * 64 * 64;   // contiguous [64][64]
  const float* Qg = q2 + (size_t)ot * 64 * 64;  // contiguous [64][64]

  // Staging with in-register 4x4 transpose. Thread owns rows rb*4..+3,
  // k-cols kb*4..+3 of the source tile.
  int rb = tid >> 4;  // 0..15
  int kb = tid & 15;  // 0..15
  {
    float4 v[4];
#pragma unroll
    for (int i = 0; i < 4; ++i)
      v[i] = ((const float4*)Tg)[(rb * 4 + i) * 16 + kb];
#pragma unroll
    for (int j = 0; j < 4; ++j) {
      float4 w;
      w.x = ((const float*)&v[0])[j];
      w.y = ((const float*)&v[1])[j];
      w.z = ((const float*)&v[2])[j];
      w.w = ((const float*)&v[3])[j];
      *reinterpret_cast<float4*>(&Tt[(kb * 4 + j) * 64 + rb * 4]) = w;
    }
#pragma unroll
    for (int i = 0; i < 4; ++i)
      v[i] = ((const float4*)Qg)[(rb * 4 + i) * 16 + kb];
#pragma unroll
    for (int j = 0; j < 4; ++j) {
      float4 w;
      w.x = ((const float*)&v[0])[j];
      w.y = ((const float*)&v[1])[j];
      w.z = ((const float*)&v[2])[j];
      w.w = ((const float*)&v[3])[j];
      *reinterpret_cast<float4*>(&Qt[(kb * 4 + j) * 64 + rb * 4]) = w;
    }
  }
  __syncthreads();

  int tx = tid & 15;  // o direction
  int ty = tid >> 4;  // b direction
  float acc[4][4] = {};
#pragma unroll
  for (int k = 0; k < 64; ++k) {
    float4 a = *reinterpret_cast<const float4*>(&Tt[k * 64 + ty * 4]);
    float4 b = *reinterpret_cast<const float4*>(&Qt[k * 64 + tx * 4]);
    const float* ap = (const float*)&a;
    const float* bp = (const float*)&b;
#pragma unroll
    for (int ii = 0; ii < 4; ++ii)
#pragma unroll
      for (int jj = 0; jj < 4; ++jj)
        acc[ii][jj] += ap[ii] * bp[jj];
  }

  int b0 = bt * 64 + ty * 4;
  int o0 = ot * 64 + tx * 4;
  float bias_r[4];
#pragma unroll
  for (int jj = 0; jj < 4; ++jj) bias_r[jj] = bias[o0 + jj];

  if (MODE == 0) {
    float m = 0.0f;
#pragma unroll
    for (int ii = 0; ii < 4; ++ii)
#pragma unroll
      for (int jj = 0; jj < 4; ++jj)
        m = fmaxf(m, fabsf(acc[ii][jj] + bias_r[jj]));
    m = wave_max(m);
    if ((tid & 63) == 0) wred[tid >> 6] = m;
    __syncthreads();
    if (tid == 0) {
      float mm = fmaxf(fmaxf(wred[0], wred[1]), fmaxf(wred[2], wred[3]));
      atomicMax(absmaxY, __float_as_uint(mm));
    }
  } else {
    float s = fq_scale(*absmaxY);
    float inv = 1.0f / s;
#pragma unroll
    for (int ii = 0; ii < 4; ++ii) {
      float4 o4;
      float* op = (float*)&o4;
#pragma unroll
      for (int jj = 0; jj < 4; ++jj) {
        float v = acc[ii][jj] + bias_r[jj];
        float q = fminf(fmaxf(rintf(v * inv), -128.0f), 127.0f) * s;
        op[jj] = fmaxf(q, 0.0f);
      }
      *reinterpret_cast<float4*>(&out[(size_t)(b0 + ii) * NOUT + o0]) = o4;
    }
  }
}

extern "C" void kernel_launch(void* const* d_in, const int* in_sizes, int n_in,
                              void* d_out, int out_size, void* d_ws,
                              size_t ws_size, hipStream_t stream) {
  (void)in_sizes; (void)n_in; (void)out_size; (void)ws_size;
  const float* x0 = (const float*)d_in[0];
  const float* x1 = (const float*)d_in[1];
  const float* f0 = (const float*)d_in[2];
  const float* f1 = (const float*)d_in[3];
  const float* f2 = (const float*)d_in[4];
  const float* bias = (const float*)d_in[5];
  float* out = (float*)d_out;

  char* ws = (char*)d_ws;
  unsigned* slots = (unsigned*)ws;              // [0]=f0 [1]=f1 [2]=f2 [3]=Y
  float* q0 = (float*)(ws + OFF_Q0);
  float* q1 = (float*)(ws + OFF_Q1);
  float* q2 = (float*)(ws + OFF_Q2);
  float* T  = (float*)(ws + OFF_T);

  hipMemsetAsync(d_ws, 0, 256, stream);
  absmax_factors<<<1024, 256, 0, stream>>>(f0, f1, f2, slots);
  quant_factors<<<1024, 256, 0, stream>>>(f0, f1, f2, slots, q0, q1, q2);
  stage1<<<512, 256, 0, stream>>>(x0, x1, q0, q1, T);
  stage2<0><<<dim3(64, 128), 256, 0, stream>>>(T, q2, bias, slots + 3, nullptr);
  stage2<1><<<dim3(64, 128), 256, 0, stream>>>(T, q2, bias, slots + 3, out);
}

// Round 7
// 280.524 us; speedup vs baseline: 1.2948x; 1.2948x over previous
//
#include <hip/hip_runtime.h>
#include <math.h>

// Shapes fixed by the reference setup_inputs
#define NB   8192
#define NR   64
#define NM   64
#define NOUT 4096

typedef __attribute__((ext_vector_type(8))) short bf16x8;
typedef __attribute__((ext_vector_type(4))) float f32x4;

// ---------------- workspace layout (bytes) ----------------
static constexpr size_t OFF_C2  = 256;                           // codes2 bf16 [4096][64] = 512KB
static constexpr size_t OFF_C0T = OFF_C2  + (size_t)NOUT*64*2;   // codes0^T bf16 [64][64] = 8KB
static constexpr size_t OFF_C1T = OFF_C0T + 64*64*2;
static constexpr size_t OFF_X0H = OFF_C1T + 64*64*2;             // x0 hi bf16 [8192][64] = 1MB
static constexpr size_t OFF_X0L = OFF_X0H + (size_t)NB*64*2;
static constexpr size_t OFF_X1H = OFF_X0L + (size_t)NB*64*2;
static constexpr size_t OFF_X1L = OFF_X1H + (size_t)NB*64*2;
static constexpr size_t OFF_TH  = OFF_X1L + (size_t)NB*64*2;     // T hi bf16 [8192][64]
static constexpr size_t OFF_TL  = OFF_TH  + (size_t)NB*64*2;
// total ~6.8MB

__device__ __forceinline__ float wave_max(float v) {
#pragma unroll
  for (int off = 32; off > 0; off >>= 1) v = fmaxf(v, __shfl_down(v, off));
  return v;
}

__device__ __forceinline__ unsigned short f2bf(float f) {
  unsigned u = __float_as_uint(f);
  unsigned r = u + 0x7fff + ((u >> 16) & 1);  // round-nearest-even
  return (unsigned short)(r >> 16);
}
__device__ __forceinline__ float bf2f(unsigned short h) {
  return __uint_as_float(((unsigned)h) << 16);
}
__device__ __forceinline__ float fq_scale(unsigned bits) {
  return fmaxf(__uint_as_float(bits) / 127.0f, 1e-8f);
}
__device__ __forceinline__ float qcode(float x, float sinv) {
  return fminf(fmaxf(rintf(x * sinv), -128.0f), 127.0f);  // exact int in bf16
}

// ---------------------------------------------------------------------------
// Kernel 1: absmax of f0,f1,f2. Blocks [0,256): f2 (float4/thread);
// [256,260): f0; [260,264): f1.
// ---------------------------------------------------------------------------
__global__ __launch_bounds__(256) void absmax_factors(
    const float* __restrict__ f0, const float* __restrict__ f1,
    const float* __restrict__ f2, unsigned* __restrict__ slots) {
  int bid = blockIdx.x, tid = threadIdx.x;
  const float* src;
  int slot;
  int i4;
  if (bid < 256)      { src = f2; slot = 2; i4 = bid * 256 + tid; }
  else if (bid < 260) { src = f0; slot = 0; i4 = (bid - 256) * 256 + tid; }
  else                { src = f1; slot = 1; i4 = (bid - 260) * 256 + tid; }
  float4 v = ((const float4*)src)[i4];
  float a = fmaxf(fmaxf(fabsf(v.x), fabsf(v.y)), fmaxf(fabsf(v.z), fabsf(v.w)));
  a = wave_max(a);
  if ((tid & 63) == 0) atomicMax(&slots[slot], __float_as_uint(a));
}

// ---------------------------------------------------------------------------
// Kernel 2: prep — quantize factors to bf16 int codes; split x0/x1 to bf16
// hi/lo. Blocks: [0,256) f2->c2; [256,768) x0; [768,1280) x1; [1280,1284)
// f0->c0t (transposed); [1284,1288) f1->c1t.
// ---------------------------------------------------------------------------
__global__ __launch_bounds__(256) void prep(
    const float* __restrict__ f0, const float* __restrict__ f1,
    const float* __restrict__ f2, const float* __restrict__ x0,
    const float* __restrict__ x1, const unsigned* __restrict__ slots,
    unsigned short* __restrict__ c0t, unsigned short* __restrict__ c1t,
    unsigned short* __restrict__ c2, unsigned short* __restrict__ x0h,
    unsigned short* __restrict__ x0l, unsigned short* __restrict__ x1h,
    unsigned short* __restrict__ x1l) {
  int bid = blockIdx.x, tid = threadIdx.x;
  if (bid < 256) {
    float sinv = 1.0f / fq_scale(slots[2]);
    int i4 = bid * 256 + tid;
    float4 v = ((const float4*)f2)[i4];
    unsigned short c0 = f2bf(qcode(v.x, sinv)), c1 = f2bf(qcode(v.y, sinv));
    unsigned short c2v = f2bf(qcode(v.z, sinv)), c3 = f2bf(qcode(v.w, sinv));
    uint2 p;
    p.x = (unsigned)c0 | ((unsigned)c1 << 16);
    p.y = (unsigned)c2v | ((unsigned)c3 << 16);
    *(uint2*)(c2 + (size_t)i4 * 4) = p;
  } else if (bid < 1280) {
    const float* x = (bid < 768) ? x0 : x1;
    unsigned short* xh = (bid < 768) ? x0h : x1h;
    unsigned short* xl = (bid < 768) ? x0l : x1l;
    int i4 = ((bid < 768) ? (bid - 256) : (bid - 768)) * 256 + tid;
    float4 v = ((const float4*)x)[i4];
    float vv[4] = {v.x, v.y, v.z, v.w};
    unsigned short h[4], lo[4];
#pragma unroll
    for (int j = 0; j < 4; ++j) {
      h[j] = f2bf(vv[j]);
      lo[j] = f2bf(vv[j] - bf2f(h[j]));
    }
    uint2 ph, pl;
    ph.x = (unsigned)h[0] | ((unsigned)h[1] << 16);
    ph.y = (unsigned)h[2] | ((unsigned)h[3] << 16);
    pl.x = (unsigned)lo[0] | ((unsigned)lo[1] << 16);
    pl.y = (unsigned)lo[2] | ((unsigned)lo[3] << 16);
    *(uint2*)(xh + (size_t)i4 * 4) = ph;
    *(uint2*)(xl + (size_t)i4 * 4) = pl;
  } else {
    const float* f = (bid < 1284) ? f0 : f1;
    unsigned short* ct = (bid < 1284) ? c0t : c1t;
    float sinv = 1.0f / fq_scale(slots[(bid < 1284) ? 0 : 1]);
    int i4 = ((bid < 1284) ? (bid - 1280) : (bid - 1284)) * 256 + tid;
    float4 v = ((const float4*)f)[i4];
    int m = (i4 * 4) / 64, r = (i4 * 4) % 64;
    ct[(size_t)(r + 0) * 64 + m] = f2bf(qcode(v.x, sinv));
    ct[(size_t)(r + 1) * 64 + m] = f2bf(qcode(v.y, sinv));
    ct[(size_t)(r + 2) * 64 + m] = f2bf(qcode(v.z, sinv));
    ct[(size_t)(r + 3) * 64 + m] = f2bf(qcode(v.w, sinv));
  }
}

// ---------------------------------------------------------------------------
// Kernel 3: stage1 — T[b,r] = s0*s1 * (x0@c0)[b,r] * (x1@c1)[b,r], stored as
// bf16 hi/lo. One wave per block, 16 rows; MFMA 16x16x32 with hi/lo A-split.
// A layout: lane holds A[l&15][ (l>>4)*8 + j + 32*ks ]. B from ct[n][k] rows.
// ---------------------------------------------------------------------------
__global__ __launch_bounds__(64) void stage1(
    const unsigned short* __restrict__ x0h, const unsigned short* __restrict__ x0l,
    const unsigned short* __restrict__ x1h, const unsigned short* __restrict__ x1l,
    const unsigned short* __restrict__ c0t, const unsigned short* __restrict__ c1t,
    const unsigned* __restrict__ slots,
    unsigned short* __restrict__ Thi, unsigned short* __restrict__ Tlo) {
  int l = threadIdx.x;
  int b0 = blockIdx.x * 16;
  int row = l & 15, kg = l >> 4;
  size_t ab = (size_t)(b0 + row) * 64 + kg * 8;

  bf16x8 a0h[2], a0l[2], a1h[2], a1l[2];
  a0h[0] = *(const bf16x8*)(x0h + ab); a0h[1] = *(const bf16x8*)(x0h + ab + 32);
  a0l[0] = *(const bf16x8*)(x0l + ab); a0l[1] = *(const bf16x8*)(x0l + ab + 32);
  a1h[0] = *(const bf16x8*)(x1h + ab); a1h[1] = *(const bf16x8*)(x1h + ab + 32);
  a1l[0] = *(const bf16x8*)(x1l + ab); a1l[1] = *(const bf16x8*)(x1l + ab + 32);

  f32x4 acc0[4] = {}, acc1[4] = {};
#pragma unroll
  for (int nf = 0; nf < 4; ++nf) {
    size_t bb = (size_t)(nf * 16 + row) * 64 + kg * 8;
    bf16x8 b0a = *(const bf16x8*)(c0t + bb), b0b = *(const bf16x8*)(c0t + bb + 32);
    bf16x8 b1a = *(const bf16x8*)(c1t + bb), b1b = *(const bf16x8*)(c1t + bb + 32);
    acc0[nf] = __builtin_amdgcn_mfma_f32_16x16x32_bf16(a0h[0], b0a, acc0[nf], 0, 0, 0);
    acc0[nf] = __builtin_amdgcn_mfma_f32_16x16x32_bf16(a0l[0], b0a, acc0[nf], 0, 0, 0);
    acc0[nf] = __builtin_amdgcn_mfma_f32_16x16x32_bf16(a0h[1], b0b, acc0[nf], 0, 0, 0);
    acc0[nf] = __builtin_amdgcn_mfma_f32_16x16x32_bf16(a0l[1], b0b, acc0[nf], 0, 0, 0);
    acc1[nf] = __builtin_amdgcn_mfma_f32_16x16x32_bf16(a1h[0], b1a, acc1[nf], 0, 0, 0);
    acc1[nf] = __builtin_amdgcn_mfma_f32_16x16x32_bf16(a1l[0], b1a, acc1[nf], 0, 0, 0);
    acc1[nf] = __builtin_amdgcn_mfma_f32_16x16x32_bf16(a1h[1], b1b, acc1[nf], 0, 0, 0);
    acc1[nf] = __builtin_amdgcn_mfma_f32_16x16x32_bf16(a1l[1], b1b, acc1[nf], 0, 0, 0);
  }

  float s01 = fq_scale(slots[0]) * fq_scale(slots[1]);
#pragma unroll
  for (int nf = 0; nf < 4; ++nf) {
#pragma unroll
    for (int j = 0; j < 4; ++j) {
      float t = s01 * acc0[nf][j] * acc1[nf][j];
      int r_out = b0 + (l >> 4) * 4 + j;
      int c_out = nf * 16 + (l & 15);
      unsigned short h = f2bf(t);
      unsigned short lo = f2bf(t - bf2f(h));
      Thi[(size_t)r_out * 64 + c_out] = h;
      Tlo[(size_t)r_out * 64 + c_out] = lo;
    }
  }
}

// ---------------------------------------------------------------------------
// Kernel 4/5: stage2 — Y = s2 * (T @ c2^T), v = Y + bias.
// MODE 0: absmax(|v|) -> slots[3]. MODE 1: out = relu(fake_quant(v)).
// Block 256 thr = 4 waves; wave tile 64(B)x64(OUT); block tile 256x64.
// No LDS: T (2MB) + c2 (0.5MB) are L2-resident; every frag load = 16B/lane.
// ---------------------------------------------------------------------------
template <int MODE>
__global__ __launch_bounds__(256) void stage2(
    const unsigned short* __restrict__ Thi, const unsigned short* __restrict__ Tlo,
    const unsigned short* __restrict__ c2, const float* __restrict__ bias,
    const unsigned* __restrict__ slots, unsigned* __restrict__ absmaxY,
    float* __restrict__ out) {
  int tid = threadIdx.x;
  int wid = tid >> 6, l = tid & 63;
  int row = l & 15, kg = l >> 4;
  int m0 = blockIdx.y * 256 + wid * 64;
  int n0 = blockIdx.x * 64;
  float s2 = fq_scale(slots[2]);

  bf16x8 bfr[4][2];
#pragma unroll
  for (int nf = 0; nf < 4; ++nf) {
    size_t bb = (size_t)(n0 + nf * 16 + row) * 64 + kg * 8;
    bfr[nf][0] = *(const bf16x8*)(c2 + bb);
    bfr[nf][1] = *(const bf16x8*)(c2 + bb + 32);
  }

  f32x4 acc[4][4] = {};
#pragma unroll
  for (int mf = 0; mf < 4; ++mf) {
    size_t ab = (size_t)(m0 + mf * 16 + row) * 64 + kg * 8;
    bf16x8 ah0 = *(const bf16x8*)(Thi + ab), ah1 = *(const bf16x8*)(Thi + ab + 32);
    bf16x8 al0 = *(const bf16x8*)(Tlo + ab), al1 = *(const bf16x8*)(Tlo + ab + 32);
#pragma unroll
    for (int nf = 0; nf < 4; ++nf) {
      acc[mf][nf] = __builtin_amdgcn_mfma_f32_16x16x32_bf16(ah0, bfr[nf][0], acc[mf][nf], 0, 0, 0);
      acc[mf][nf] = __builtin_amdgcn_mfma_f32_16x16x32_bf16(al0, bfr[nf][0], acc[mf][nf], 0, 0, 0);
      acc[mf][nf] = __builtin_amdgcn_mfma_f32_16x16x32_bf16(ah1, bfr[nf][1], acc[mf][nf], 0, 0, 0);
      acc[mf][nf] = __builtin_amdgcn_mfma_f32_16x16x32_bf16(al1, bfr[nf][1], acc[mf][nf], 0, 0, 0);
    }
  }

  float bs[4];
#pragma unroll
  for (int nf = 0; nf < 4; ++nf) bs[nf] = bias[n0 + nf * 16 + (l & 15)];

  if (MODE == 0) {
    float m = 0.0f;
#pragma unroll
    for (int mf = 0; mf < 4; ++mf)
#pragma unroll
      for (int nf = 0; nf < 4; ++nf)
#pragma unroll
        for (int j = 0; j < 4; ++j)
          m = fmaxf(m, fabsf(s2 * acc[mf][nf][j] + bs[nf]));
    m = wave_max(m);
    if ((tid & 63) == 0) atomicMax(absmaxY, __float_as_uint(m));
  } else {
    float sY = fq_scale(*absmaxY);
    float inv = 1.0f / sY;
#pragma unroll
    for (int mf = 0; mf < 4; ++mf) {
      int r0 = m0 + mf * 16 + (l >> 4) * 4;
#pragma unroll
      for (int nf = 0; nf < 4; ++nf) {
        int c = n0 + nf * 16 + (l & 15);
#pragma unroll
        for (int j = 0; j < 4; ++j) {
          float v = s2 * acc[mf][nf][j] + bs[nf];
          float q = fminf(fmaxf(rintf(v * inv), -128.0f), 127.0f) * sY;
          out[(size_t)(r0 + j) * NOUT + c] = fmaxf(q, 0.0f);
        }
      }
    }
  }
}

extern "C" void kernel_launch(void* const* d_in, const int* in_sizes, int n_in,
                              void* d_out, int out_size, void* d_ws,
                              size_t ws_size, hipStream_t stream) {
  (void)in_sizes; (void)n_in; (void)out_size; (void)ws_size;
  const float* x0 = (const float*)d_in[0];
  const float* x1 = (const float*)d_in[1];
  const float* f0 = (const float*)d_in[2];
  const float* f1 = (const float*)d_in[3];
  const float* f2 = (const float*)d_in[4];
  const float* bias = (const float*)d_in[5];
  float* out = (float*)d_out;

  char* ws = (char*)d_ws;
  unsigned* slots = (unsigned*)ws;  // [0]=f0 [1]=f1 [2]=f2 [3]=Y
  unsigned short* c2  = (unsigned short*)(ws + OFF_C2);
  unsigned short* c0t = (unsigned short*)(ws + OFF_C0T);
  unsigned short* c1t = (unsigned short*)(ws + OFF_C1T);
  unsigned short* x0h = (unsigned short*)(ws + OFF_X0H);
  unsigned short* x0l = (unsigned short*)(ws + OFF_X0L);
  unsigned short* x1h = (unsigned short*)(ws + OFF_X1H);
  unsigned short* x1l = (unsigned short*)(ws + OFF_X1L);
  unsigned short* Thi = (unsigned short*)(ws + OFF_TH);
  unsigned short* Tlo = (unsigned short*)(ws + OFF_TL);

  hipMemsetAsync(d_ws, 0, 256, stream);
  absmax_factors<<<264, 256, 0, stream>>>(f0, f1, f2, slots);
  prep<<<1288, 256, 0, stream>>>(f0, f1, f2, x0, x1, slots, c0t, c1t, c2,
                                 x0h, x0l, x1h, x1l);
  stage1<<<512, 64, 0, stream>>>(x0h, x0l, x1h, x1l, c0t, c1t, slots, Thi, Tlo);
  stage2<0><<<dim3(64, 32), 256, 0, stream>>>(Thi, Tlo, c2, bias, slots,
                                              slots + 3, nullptr);
  stage2<1><<<dim3(64, 32), 256, 0, stream>>>(Thi, Tlo, c2, bias, slots,
                                              slots + 3, out);
}

// Round 9
// 174.674 us; speedup vs baseline: 2.0794x; 1.6060x over previous
//
#include <hip/hip_runtime.h>
#include <math.h>

// Shapes fixed by the reference setup_inputs
#define NB   8192
#define NR   64
#define NOUT 4096

typedef __attribute__((ext_vector_type(8))) short bf16x8;
typedef __attribute__((ext_vector_type(4))) float f32x4;

// ---------------------------------------------------------------------------
// Fragment-tiled operand layout (shorts):
//   FT[t][ks][lane][j]  at  t*1024 + ks*512 + lane*8 + j
// holds M[t*16 + (lane&15)][ks*32 + (lane>>4)*8 + j] of a row-major [rows][64]
// matrix. A wave's MFMA fragment load is then base + lane*16B => coalesced.
// ---------------------------------------------------------------------------

// workspace layout (bytes)
static constexpr size_t OFF_FC2  = 256;                      // 256 tiles * 2KB = 512KB
static constexpr size_t OFF_FC0T = OFF_FC2  + 256 * 2048;    // 4 tiles * 2KB = 8KB
static constexpr size_t OFF_FC1T = OFF_FC0T + 4 * 2048;
static constexpr size_t OFF_FX0H = OFF_FC1T + 4 * 2048;      // 512 tiles * 2KB = 1MB
static constexpr size_t OFF_FX0L = OFF_FX0H + 512 * 2048;
static constexpr size_t OFF_FX1H = OFF_FX0L + 512 * 2048;
static constexpr size_t OFF_FX1L = OFF_FX1H + 512 * 2048;
static constexpr size_t OFF_FTH  = OFF_FX1L + 512 * 2048;
static constexpr size_t OFF_FTL  = OFF_FTH  + 512 * 2048;
static constexpr size_t OFF_BMAX = OFF_FTL  + 512 * 2048;    // 2048 f32 = 8KB
// total ~6.85MB

__device__ __forceinline__ float wave_max(float v) {
#pragma unroll
  for (int off = 32; off > 0; off >>= 1) v = fmaxf(v, __shfl_down(v, off));
  return v;
}

__device__ __forceinline__ unsigned short f2bf(float f) {
  unsigned u = __float_as_uint(f);
  unsigned r = u + 0x7fff + ((u >> 16) & 1);  // round-nearest-even
  return (unsigned short)(r >> 16);
}
__device__ __forceinline__ float bf2f(unsigned short h) {
  return __uint_as_float(((unsigned)h) << 16);
}
__device__ __forceinline__ float fq_scale(unsigned bits) {
  return fmaxf(__uint_as_float(bits) / 127.0f, 1e-8f);
}
__device__ __forceinline__ float qcode(float x, float sinv) {
  return fminf(fmaxf(rintf(x * sinv), -128.0f), 127.0f);  // exact int in bf16
}

// frag-tiled short index for element (row, k) of a [rows][64] matrix
__device__ __forceinline__ int ft_idx(int row, int k) {
  return (row >> 4) * 1024 + (k >> 5) * 512 +
         ((row & 15) + (((k & 31) >> 3) << 4)) * 8 + (k & 7);
}

// ---------------------------------------------------------------------------
// Kernel 1: absmax of f0,f1,f2. One atomic per BLOCK (LDS reduce first).
// Blocks [0,256): f2; [256,260): f0; [260,264): f1.
// ---------------------------------------------------------------------------
__global__ __launch_bounds__(256) void absmax_factors(
    const float* __restrict__ f0, const float* __restrict__ f1,
    const float* __restrict__ f2, unsigned* __restrict__ slots) {
  __shared__ float wred[4];
  int bid = blockIdx.x, tid = threadIdx.x;
  const float* src;
  int slot, i4;
  if (bid < 256)      { src = f2; slot = 2; i4 = bid * 256 + tid; }
  else if (bid < 260) { src = f0; slot = 0; i4 = (bid - 256) * 256 + tid; }
  else                { src = f1; slot = 1; i4 = (bid - 260) * 256 + tid; }
  float4 v = ((const float4*)src)[i4];
  float a = fmaxf(fmaxf(fabsf(v.x), fabsf(v.y)), fmaxf(fabsf(v.z), fabsf(v.w)));
  a = wave_max(a);
  if ((tid & 63) == 0) wred[tid >> 6] = a;
  __syncthreads();
  if (tid == 0) {
    float m = fmaxf(fmaxf(wred[0], wred[1]), fmaxf(wred[2], wred[3]));
    atomicMax(&slots[slot], __float_as_uint(m));
  }
}

// ---------------------------------------------------------------------------
// Kernel 2: prep — quantize factors to bf16 int codes and split x0/x1 into
// bf16 hi/lo, ALL stored in frag-tiled layout.
// Blocks: [0,256) f2->FC2; [256,768) x0; [768,1280) x1; [1280,1284) f0;
// [1284,1288) f1.
// ---------------------------------------------------------------------------
__global__ __launch_bounds__(256) void prep(
    const float* __restrict__ f0, const float* __restrict__ f1,
    const float* __restrict__ f2, const float* __restrict__ x0,
    const float* __restrict__ x1, const unsigned* __restrict__ slots,
    unsigned short* __restrict__ fc0t, unsigned short* __restrict__ fc1t,
    unsigned short* __restrict__ fc2, unsigned short* __restrict__ fx0h,
    unsigned short* __restrict__ fx0l, unsigned short* __restrict__ fx1h,
    unsigned short* __restrict__ fx1l) {
  int bid = blockIdx.x, tid = threadIdx.x;
  if (bid < 256) {
    float sinv = 1.0f / fq_scale(slots[2]);
    int i4 = bid * 256 + tid;
    int e = i4 * 4, m = e >> 6, r0 = e & 63;
    float4 v = ((const float4*)f2)[i4];
    unsigned short c0 = f2bf(qcode(v.x, sinv)), c1 = f2bf(qcode(v.y, sinv));
    unsigned short cc2 = f2bf(qcode(v.z, sinv)), c3 = f2bf(qcode(v.w, sinv));
    uint2 p;
    p.x = (unsigned)c0 | ((unsigned)c1 << 16);
    p.y = (unsigned)cc2 | ((unsigned)c3 << 16);
    *(uint2*)(fc2 + ft_idx(m, r0)) = p;  // 4 consecutive k live in same lane
  } else if (bid < 1280) {
    const float* x = (bid < 768) ? x0 : x1;
    unsigned short* xh = (bid < 768) ? fx0h : fx1h;
    unsigned short* xl = (bid < 768) ? fx0l : fx1l;
    int i4 = ((bid < 768) ? (bid - 256) : (bid - 768)) * 256 + tid;
    int e = i4 * 4, m = e >> 6, r0 = e & 63;
    float4 v = ((const float4*)x)[i4];
    float vv[4] = {v.x, v.y, v.z, v.w};
    unsigned short h[4], lo[4];
#pragma unroll
    for (int j = 0; j < 4; ++j) {
      h[j] = f2bf(vv[j]);
      lo[j] = f2bf(vv[j] - bf2f(h[j]));
    }
    uint2 ph, pl;
    ph.x = (unsigned)h[0] | ((unsigned)h[1] << 16);
    ph.y = (unsigned)h[2] | ((unsigned)h[3] << 16);
    pl.x = (unsigned)lo[0] | ((unsigned)lo[1] << 16);
    pl.y = (unsigned)lo[2] | ((unsigned)lo[3] << 16);
    int idx = ft_idx(m, r0);
    *(uint2*)(xh + idx) = ph;
    *(uint2*)(xl + idx) = pl;
  } else {
    // f0/f1 -> transposed code matrix Bt[r][m], frag-tiled
    const float* f = (bid < 1284) ? f0 : f1;
    unsigned short* ct = (bid < 1284) ? fc0t : fc1t;
    float sinv = 1.0f / fq_scale(slots[(bid < 1284) ? 0 : 1]);
    int i4 = ((bid < 1284) ? (bid - 1280) : (bid - 1284)) * 256 + tid;
    int e = i4 * 4, m = e >> 6, r0 = e & 63;  // m = f-row (k dim), r = factor col
    float4 v = ((const float4*)f)[i4];
    float vv[4] = {v.x, v.y, v.z, v.w};
#pragma unroll
    for (int q = 0; q < 4; ++q)
      ct[ft_idx(r0 + q, m)] = f2bf(qcode(vv[q], sinv));
  }
}

// ---------------------------------------------------------------------------
// Kernel 3: stage1 — T = s0*s1 * (x0@c0) ⊙ (x1@c1), stored bf16 hi/lo in
// frag-tiled layout. 4 waves/block; wave nf handles output col-tile nf of the
// block's 16-row b-tile. All operand loads coalesced via frag tiling.
// ---------------------------------------------------------------------------
__global__ __launch_bounds__(256) void stage1(
    const unsigned short* __restrict__ fx0h, const unsigned short* __restrict__ fx0l,
    const unsigned short* __restrict__ fx1h, const unsigned short* __restrict__ fx1l,
    const unsigned short* __restrict__ fc0t, const unsigned short* __restrict__ fc1t,
    const unsigned* __restrict__ slots,
    unsigned short* __restrict__ fth, unsigned short* __restrict__ ftl) {
  int tid = threadIdx.x;
  int l = tid & 63, nf = tid >> 6;
  int t = blockIdx.x;  // b-tile (16 rows)
  int abase = t * 1024 + l * 8;

  bf16x8 a0h0 = *(const bf16x8*)(fx0h + abase), a0h1 = *(const bf16x8*)(fx0h + abase + 512);
  bf16x8 a0l0 = *(const bf16x8*)(fx0l + abase), a0l1 = *(const bf16x8*)(fx0l + abase + 512);
  bf16x8 a1h0 = *(const bf16x8*)(fx1h + abase), a1h1 = *(const bf16x8*)(fx1h + abase + 512);
  bf16x8 a1l0 = *(const bf16x8*)(fx1l + abase), a1l1 = *(const bf16x8*)(fx1l + abase + 512);

  int bbase = nf * 1024 + l * 8;
  bf16x8 b0a = *(const bf16x8*)(fc0t + bbase), b0b = *(const bf16x8*)(fc0t + bbase + 512);
  bf16x8 b1a = *(const bf16x8*)(fc1t + bbase), b1b = *(const bf16x8*)(fc1t + bbase + 512);

  f32x4 acc0 = {}, acc1 = {};
  acc0 = __builtin_amdgcn_mfma_f32_16x16x32_bf16(a0h0, b0a, acc0, 0, 0, 0);
  acc0 = __builtin_amdgcn_mfma_f32_16x16x32_bf16(a0l0, b0a, acc0, 0, 0, 0);
  acc0 = __builtin_amdgcn_mfma_f32_16x16x32_bf16(a0h1, b0b, acc0, 0, 0, 0);
  acc0 = __builtin_amdgcn_mfma_f32_16x16x32_bf16(a0l1, b0b, acc0, 0, 0, 0);
  acc1 = __builtin_amdgcn_mfma_f32_16x16x32_bf16(a1h0, b1a, acc1, 0, 0, 0);
  acc1 = __builtin_amdgcn_mfma_f32_16x16x32_bf16(a1l0, b1a, acc1, 0, 0, 0);
  acc1 = __builtin_amdgcn_mfma_f32_16x16x32_bf16(a1h1, b1b, acc1, 0, 0, 0);
  acc1 = __builtin_amdgcn_mfma_f32_16x16x32_bf16(a1l1, b1b, acc1, 0, 0, 0);

  float s01 = fq_scale(slots[0]) * fq_scale(slots[1]);
#pragma unroll
  for (int j = 0; j < 4; ++j) {
    float tv = s01 * acc0[j] * acc1[j];
    // C element: row_in_tile = (l>>4)*4 + j, col r = nf*16 + (l&15)
    int row_in = (l >> 4) * 4 + j;
    int r = nf * 16 + (l & 15);
    int idx = t * 1024 + (r >> 5) * 512 +
              (row_in + (((r & 31) >> 3) << 4)) * 8 + (r & 7);
    unsigned short h = f2bf(tv);
    fth[idx] = h;
    ftl[idx] = f2bf(tv - bf2f(h));
  }
}

// ---------------------------------------------------------------------------
// Kernel 4/5: stage2 — Y = s2 * (T @ c2^T), v = Y + bias.
// MODE 0: per-block max(|v|) -> bmax[block] (plain store, no atomics).
// MODE 1: out = relu(fake_quant(v)) with scale from slots[3].
// 4 waves/block; wave tile 64(B)x64(OUT); block tile 256x64. All fragment
// loads coalesced (frag-tiled operands, L2-resident).
// ---------------------------------------------------------------------------
template <int MODE>
__global__ __launch_bounds__(256) void stage2(
    const unsigned short* __restrict__ fth, const unsigned short* __restrict__ ftl,
    const unsigned short* __restrict__ fc2, const float* __restrict__ bias,
    const unsigned* __restrict__ slots, float* __restrict__ bmax,
    const unsigned* __restrict__ absmaxY, float* __restrict__ out) {
  __shared__ float wred[4];
  int tid = threadIdx.x;
  int wid = tid >> 6, l = tid & 63;
  int m0 = blockIdx.y * 256 + wid * 64;
  int n0 = blockIdx.x * 64;
  int mt0 = m0 >> 4, nt0 = n0 >> 4;
  float s2 = fq_scale(slots[2]);

  bf16x8 bfr[4][2];
#pragma unroll
  for (int nf = 0; nf < 4; ++nf) {
    int bb = (nt0 + nf) * 1024 + l * 8;
    bfr[nf][0] = *(const bf16x8*)(fc2 + bb);
    bfr[nf][1] = *(const bf16x8*)(fc2 + bb + 512);
  }

  f32x4 acc[4][4] = {};
#pragma unroll
  for (int mf = 0; mf < 4; ++mf) {
    int ab = (mt0 + mf) * 1024 + l * 8;
    bf16x8 ah0 = *(const bf16x8*)(fth + ab), ah1 = *(const bf16x8*)(fth + ab + 512);
    bf16x8 al0 = *(const bf16x8*)(ftl + ab), al1 = *(const bf16x8*)(ftl + ab + 512);
#pragma unroll
    for (int nf = 0; nf < 4; ++nf) {
      acc[mf][nf] = __builtin_amdgcn_mfma_f32_16x16x32_bf16(ah0, bfr[nf][0], acc[mf][nf], 0, 0, 0);
      acc[mf][nf] = __builtin_amdgcn_mfma_f32_16x16x32_bf16(al0, bfr[nf][0], acc[mf][nf], 0, 0, 0);
      acc[mf][nf] = __builtin_amdgcn_mfma_f32_16x16x32_bf16(ah1, bfr[nf][1], acc[mf][nf], 0, 0, 0);
      acc[mf][nf] = __builtin_amdgcn_mfma_f32_16x16x32_bf16(al1, bfr[nf][1], acc[mf][nf], 0, 0, 0);
    }
  }

  float bs[4];
#pragma unroll
  for (int nf = 0; nf < 4; ++nf) bs[nf] = bias[n0 + nf * 16 + (l & 15)];

  if (MODE == 0) {
    float m = 0.0f;
#pragma unroll
    for (int mf = 0; mf < 4; ++mf)
#pragma unroll
      for (int nf = 0; nf < 4; ++nf)
#pragma unroll
        for (int j = 0; j < 4; ++j)
          m = fmaxf(m, fabsf(s2 * acc[mf][nf][j] + bs[nf]));
    m = wave_max(m);
    if ((tid & 63) == 0) wred[tid >> 6] = m;
    __syncthreads();
    if (tid == 0) {
      float mm = fmaxf(fmaxf(wred[0], wred[1]), fmaxf(wred[2], wred[3]));
      bmax[blockIdx.y * gridDim.x + blockIdx.x] = mm;  // no atomics
    }
  } else {
    float sY = fq_scale(*absmaxY);
    float inv = 1.0f / sY;
#pragma unroll
    for (int mf = 0; mf < 4; ++mf) {
      int r0 = m0 + mf * 16 + (l >> 4) * 4;
#pragma unroll
      for (int nf = 0; nf < 4; ++nf) {
        int c = n0 + nf * 16 + (l & 15);
#pragma unroll
        for (int j = 0; j < 4; ++j) {
          float v = s2 * acc[mf][nf][j] + bs[nf];
          float q = fminf(fmaxf(rintf(v * inv), -128.0f), 127.0f) * sY;
          out[(size_t)(r0 + j) * NOUT + c] = fmaxf(q, 0.0f);
        }
      }
    }
  }
}

// ---------------------------------------------------------------------------
// Kernel: reduce 2048 block maxima -> slots[3] (single block, atomic-free)
// ---------------------------------------------------------------------------
__global__ __launch_bounds__(256) void reduce_bmax(
    const float* __restrict__ bmax, unsigned* __restrict__ slot) {
  __shared__ float wred[4];
  int tid = threadIdx.x;
  float m = 0.0f;
#pragma unroll
  for (int i = 0; i < 8; ++i) m = fmaxf(m, bmax[tid + i * 256]);
  m = wave_max(m);
  if ((tid & 63) == 0) wred[tid >> 6] = m;
  __syncthreads();
  if (tid == 0) {
    float mm = fmaxf(fmaxf(wred[0], wred[1]), fmaxf(wred[2], wred[3]));
    *slot = __float_as_uint(mm);
  }
}

extern "C" void kernel_launch(void* const* d_in, const int* in_sizes, int n_in,
                              void* d_out, int out_size, void* d_ws,
                              size_t ws_size, hipStream_t stream) {
  (void)in_sizes; (void)n_in; (void)out_size; (void)ws_size;
  const float* x0 = (const float*)d_in[0];
  const float* x1 = (const float*)d_in[1];
  const float* f0 = (const float*)d_in[2];
  const float* f1 = (const float*)d_in[3];
  const float* f2 = (const float*)d_in[4];
  const float* bias = (const float*)d_in[5];
  float* out = (float*)d_out;

  char* ws = (char*)d_ws;
  unsigned* slots = (unsigned*)ws;  // [0]=f0 [1]=f1 [2]=f2 [3]=Y
  unsigned short* fc2  = (unsigned short*)(ws + OFF_FC2);
  unsigned short* fc0t = (unsigned short*)(ws + OFF_FC0T);
  unsigned short* fc1t = (unsigned short*)(ws + OFF_FC1T);
  unsigned short* fx0h = (unsigned short*)(ws + OFF_FX0H);
  unsigned short* fx0l = (unsigned short*)(ws + OFF_FX0L);
  unsigned short* fx1h = (unsigned short*)(ws + OFF_FX1H);
  unsigned short* fx1l = (unsigned short*)(ws + OFF_FX1L);
  unsigned short* fth  = (unsigned short*)(ws + OFF_FTH);
  unsigned short* ftl  = (unsigned short*)(ws + OFF_FTL);
  float* bmax = (float*)(ws + OFF_BMAX);

  hipMemsetAsync(d_ws, 0, 256, stream);
  absmax_factors<<<264, 256, 0, stream>>>(f0, f1, f2, slots);
  prep<<<1288, 256, 0, stream>>>(f0, f1, f2, x0, x1, slots, fc0t, fc1t, fc2,
                                 fx0h, fx0l, fx1h, fx1l);
  stage1<<<512, 256, 0, stream>>>(fx0h, fx0l, fx1h, fx1l, fc0t, fc1t, slots,
                                  fth, ftl);
  stage2<0><<<dim3(64, 32), 256, 0, stream>>>(fth, ftl, fc2, bias, slots,
                                              bmax, nullptr, nullptr);
  reduce_bmax<<<1, 256, 0, stream>>>(bmax, slots + 3);
  stage2<1><<<dim3(64, 32), 256, 0, stream>>>(fth, ftl, fc2, bias, slots,
                                              nullptr, slots + 3, out);
}

// Round 10
// 170.651 us; speedup vs baseline: 2.1285x; 1.0236x over previous
//
#include <hip/hip_runtime.h>
#include <math.h>

// Shapes fixed by the reference setup_inputs
#define NB   8192
#define NR   64
#define NOUT 4096

typedef __attribute__((ext_vector_type(8))) short bf16x8;
typedef __attribute__((ext_vector_type(4))) float f32x4;

// ---------------------------------------------------------------------------
// Fragment-tiled operand layout (shorts):
//   FT[t][ks][lane][j]  at  t*1024 + ks*512 + lane*8 + j
// holds M[t*16 + (lane&15)][ks*32 + (lane>>4)*8 + j] of a row-major [rows][64]
// matrix. A wave's MFMA fragment load is then base + lane*16B => coalesced.
// ---------------------------------------------------------------------------

// workspace layout (bytes). slots_f[2]=s2 scale, slots_f[3]=sY scale.
static constexpr size_t OFF_PF2  = 256;                     // 256 f32 partial maxes
static constexpr size_t OFF_BMAX = 2048;                    // 2048 f32
static constexpr size_t OFF_FC2  = 16384;                   // 256 tiles * 2KB = 512KB
static constexpr size_t OFF_FTH  = OFF_FC2 + 256 * 2048;    // 2MB
static constexpr size_t OFF_FTL  = OFF_FTH + (size_t)512 * 2048 * 2;
// total ~4.7MB

__device__ __forceinline__ float wave_max(float v) {
#pragma unroll
  for (int off = 32; off > 0; off >>= 1) v = fmaxf(v, __shfl_down(v, off));
  return v;
}

__device__ __forceinline__ unsigned short f2bf(float f) {
  unsigned u = __float_as_uint(f);
  unsigned r = u + 0x7fff + ((u >> 16) & 1);  // round-nearest-even
  return (unsigned short)(r >> 16);
}
__device__ __forceinline__ float bf2f(unsigned short h) {
  return __uint_as_float(((unsigned)h) << 16);
}
__device__ __forceinline__ float qcode(float x, float sinv) {
  return fminf(fmaxf(rintf(x * sinv), -128.0f), 127.0f);  // exact int in bf16
}

// frag-tiled short index for element (row, k) of a [rows][64] matrix
__device__ __forceinline__ int ft_idx(int row, int k) {
  return (row >> 4) * 1024 + (k >> 5) * 512 +
         ((row & 15) + (((k & 31) >> 3) << 4)) * 8 + (k & 7);
}

__device__ __forceinline__ void split8(float4 a, float4 b, bf16x8& h, bf16x8& lo) {
  float v[8] = {a.x, a.y, a.z, a.w, b.x, b.y, b.z, b.w};
#pragma unroll
  for (int j = 0; j < 8; ++j) {
    unsigned short hh = f2bf(v[j]);
    h[j] = (short)hh;
    lo[j] = (short)f2bf(v[j] - bf2f(hh));
  }
}

// ---------------------------------------------------------------------------
// Kernel 1: f2 per-block partial absmax -> pf2[256]. No atomics, no init.
// ---------------------------------------------------------------------------
__global__ __launch_bounds__(256) void absmax_f2(
    const float* __restrict__ f2, float* __restrict__ pf2) {
  __shared__ float wred[4];
  int tid = threadIdx.x;
  float4 v = ((const float4*)f2)[blockIdx.x * 256 + tid];
  float a = fmaxf(fmaxf(fabsf(v.x), fabsf(v.y)), fmaxf(fabsf(v.z), fabsf(v.w)));
  a = wave_max(a);
  if ((tid & 63) == 0) wred[tid >> 6] = a;
  __syncthreads();
  if (tid == 0)
    pf2[blockIdx.x] = fmaxf(fmaxf(wred[0], wred[1]), fmaxf(wred[2], wred[3]));
}

// ---------------------------------------------------------------------------
// Kernel 2: reduce pf2 -> s2 (block 0 stores it), quantize f2 -> fc2
// (frag-tiled bf16 int codes).
// ---------------------------------------------------------------------------
__global__ __launch_bounds__(256) void prep_f2(
    const float* __restrict__ f2, const float* __restrict__ pf2,
    float* __restrict__ slots_f, unsigned short* __restrict__ fc2) {
  __shared__ float wred[4];
  int tid = threadIdx.x, bid = blockIdx.x;
  float a = pf2[tid];
  a = wave_max(a);
  if ((tid & 63) == 0) wred[tid >> 6] = a;
  __syncthreads();
  float am = fmaxf(fmaxf(wred[0], wred[1]), fmaxf(wred[2], wred[3]));
  float s2 = fmaxf(am * (1.0f / 127.0f), 1e-8f);
  if (bid == 0 && tid == 0) slots_f[2] = s2;
  float sinv = 1.0f / s2;
  int i4 = bid * 256 + tid;
  int e = i4 * 4, m = e >> 6, r0 = e & 63;
  float4 v = ((const float4*)f2)[i4];
  unsigned short c0 = f2bf(qcode(v.x, sinv)), c1 = f2bf(qcode(v.y, sinv));
  unsigned short cc2 = f2bf(qcode(v.z, sinv)), c3 = f2bf(qcode(v.w, sinv));
  uint2 p;
  p.x = (unsigned)c0 | ((unsigned)c1 << 16);
  p.y = (unsigned)cc2 | ((unsigned)c3 << 16);
  *(uint2*)(fc2 + ft_idx(m, r0)) = p;
}

// ---------------------------------------------------------------------------
// Kernel 3: stage1_fused — per 16-row b-tile:
//   (a) recompute s0,s1 from raw f0,f1 (16KB each, L2-hot; deterministic ->
//       identical across blocks), (b) quantize codes into LDS (frag layout),
//   (c) A = hi/lo split of x0/x1 loaded straight from fp32 global,
//   (d) 8 MFMAs -> T = s0*s1*(x0@c0)⊙(x1@c1), stored bf16 hi/lo frag-tiled.
// Kills the prep x-roundtrip (8.4MB) and the f0/f1 absmax/prep branches.
// ---------------------------------------------------------------------------
__global__ __launch_bounds__(256) void stage1_fused(
    const float* __restrict__ x0, const float* __restrict__ x1,
    const float* __restrict__ f0, const float* __restrict__ f1,
    unsigned short* __restrict__ fth, unsigned short* __restrict__ ftl) {
  __shared__ float wred0[4], wred1[4];
  __shared__ unsigned short c0s[4096], c1s[4096];
  int tid = threadIdx.x;

  // (a) scales
  float a0 = 0.0f, a1 = 0.0f;
#pragma unroll
  for (int i = 0; i < 4; ++i) {
    float4 v0 = ((const float4*)f0)[tid + i * 256];
    float4 v1 = ((const float4*)f1)[tid + i * 256];
    a0 = fmaxf(a0, fmaxf(fmaxf(fabsf(v0.x), fabsf(v0.y)),
                         fmaxf(fabsf(v0.z), fabsf(v0.w))));
    a1 = fmaxf(a1, fmaxf(fmaxf(fabsf(v1.x), fabsf(v1.y)),
                         fmaxf(fabsf(v1.z), fabsf(v1.w))));
  }
  a0 = wave_max(a0);
  a1 = wave_max(a1);
  if ((tid & 63) == 0) { wred0[tid >> 6] = a0; wred1[tid >> 6] = a1; }
  __syncthreads();
  float am0 = fmaxf(fmaxf(wred0[0], wred0[1]), fmaxf(wred0[2], wred0[3]));
  float am1 = fmaxf(fmaxf(wred1[0], wred1[1]), fmaxf(wred1[2], wred1[3]));
  float s0 = fmaxf(am0 * (1.0f / 127.0f), 1e-8f);
  float s1 = fmaxf(am1 * (1.0f / 127.0f), 1e-8f);
  float sinv0 = 1.0f / s0, sinv1 = 1.0f / s1;

  // (b) codes into LDS, frag layout for Bt[r][m]
  int m = tid >> 2, rb = (tid & 3) * 16;
#pragma unroll
  for (int i = 0; i < 4; ++i) {
    float4 v0 = ((const float4*)f0)[tid * 4 + i];
    float4 v1 = ((const float4*)f1)[tid * 4 + i];
    float w0[4] = {v0.x, v0.y, v0.z, v0.w};
    float w1[4] = {v1.x, v1.y, v1.z, v1.w};
#pragma unroll
    for (int j = 0; j < 4; ++j) {
      int r = rb + i * 4 + j;
      c0s[ft_idx(r, m)] = f2bf(qcode(w0[j], sinv0));
      c1s[ft_idx(r, m)] = f2bf(qcode(w1[j], sinv1));
    }
  }
  __syncthreads();

  // (c) A from global fp32, hi/lo split in-register
  int l = tid & 63, nf = tid >> 6;
  int b0 = blockIdx.x * 16;
  int row = b0 + (l & 15), kb = (l >> 4) * 8;
  const float* p0 = x0 + (size_t)row * 64 + kb;
  const float* p1 = x1 + (size_t)row * 64 + kb;
  bf16x8 a0h0, a0l0, a0h1, a0l1, a1h0, a1l0, a1h1, a1l1;
  split8(*(const float4*)p0, *(const float4*)(p0 + 4), a0h0, a0l0);
  split8(*(const float4*)(p0 + 32), *(const float4*)(p0 + 36), a0h1, a0l1);
  split8(*(const float4*)p1, *(const float4*)(p1 + 4), a1h0, a1l0);
  split8(*(const float4*)(p1 + 32), *(const float4*)(p1 + 36), a1h1, a1l1);

  bf16x8 b0a = *(const bf16x8*)(c0s + nf * 1024 + l * 8);
  bf16x8 b0b = *(const bf16x8*)(c0s + nf * 1024 + l * 8 + 512);
  bf16x8 b1a = *(const bf16x8*)(c1s + nf * 1024 + l * 8);
  bf16x8 b1b = *(const bf16x8*)(c1s + nf * 1024 + l * 8 + 512);

  // (d) MFMA + epilogue
  f32x4 acc0 = {}, acc1 = {};
  acc0 = __builtin_amdgcn_mfma_f32_16x16x32_bf16(a0h0, b0a, acc0, 0, 0, 0);
  acc0 = __builtin_amdgcn_mfma_f32_16x16x32_bf16(a0l0, b0a, acc0, 0, 0, 0);
  acc0 = __builtin_amdgcn_mfma_f32_16x16x32_bf16(a0h1, b0b, acc0, 0, 0, 0);
  acc0 = __builtin_amdgcn_mfma_f32_16x16x32_bf16(a0l1, b0b, acc0, 0, 0, 0);
  acc1 = __builtin_amdgcn_mfma_f32_16x16x32_bf16(a1h0, b1a, acc1, 0, 0, 0);
  acc1 = __builtin_amdgcn_mfma_f32_16x16x32_bf16(a1l0, b1a, acc1, 0, 0, 0);
  acc1 = __builtin_amdgcn_mfma_f32_16x16x32_bf16(a1h1, b1b, acc1, 0, 0, 0);
  acc1 = __builtin_amdgcn_mfma_f32_16x16x32_bf16(a1l1, b1b, acc1, 0, 0, 0);

  float s01 = s0 * s1;
#pragma unroll
  for (int j = 0; j < 4; ++j) {
    float tv = s01 * acc0[j] * acc1[j];
    int row_in = (l >> 4) * 4 + j;
    int r = nf * 16 + (l & 15);
    int idx = blockIdx.x * 1024 + (r >> 5) * 512 +
              (row_in + (((r & 31) >> 3) << 4)) * 8 + (r & 7);
    unsigned short h = f2bf(tv);
    fth[idx] = h;
    ftl[idx] = f2bf(tv - bf2f(h));
  }
}

// ---------------------------------------------------------------------------
// Kernel 4/6: stage2 — Y = s2 * (T @ c2^T), v = Y + bias.
// MODE 0: per-block max(|v|) -> bmax[flat]. MODE 1: out = relu(fq(v)).
// 1D grid 2048, XCD-swizzled: xcd = flat&7 owns m-tiles [xcd*4, xcd*4+4)
// so T rows stay in that XCD's L2 across the 64 n-tiles.
// ---------------------------------------------------------------------------
template <int MODE>
__global__ __launch_bounds__(256) void stage2(
    const unsigned short* __restrict__ fth, const unsigned short* __restrict__ ftl,
    const unsigned short* __restrict__ fc2, const float* __restrict__ bias,
    const float* __restrict__ slots_f, float* __restrict__ bmax,
    float* __restrict__ out) {
  __shared__ float wred[4];
  int flat = blockIdx.x;
  int xcd = flat & 7, local = flat >> 3;
  int mt = xcd * 4 + (local >> 6);   // 0..31 (block m-tile of 256 rows)
  int nt = local & 63;               // 0..63 (block n-tile of 64 cols)
  int tid = threadIdx.x;
  int wid = tid >> 6, l = tid & 63;
  int m0 = mt * 256 + wid * 64;
  int n0 = nt * 64;
  int mt0 = m0 >> 4, nt0 = n0 >> 4;
  float s2 = slots_f[2];

  bf16x8 bfr[4][2];
#pragma unroll
  for (int nf = 0; nf < 4; ++nf) {
    int bb = (nt0 + nf) * 1024 + l * 8;
    bfr[nf][0] = *(const bf16x8*)(fc2 + bb);
    bfr[nf][1] = *(const bf16x8*)(fc2 + bb + 512);
  }

  f32x4 acc[4][4] = {};
#pragma unroll
  for (int mf = 0; mf < 4; ++mf) {
    int ab = (mt0 + mf) * 1024 + l * 8;
    bf16x8 ah0 = *(const bf16x8*)(fth + ab), ah1 = *(const bf16x8*)(fth + ab + 512);
    bf16x8 al0 = *(const bf16x8*)(ftl + ab), al1 = *(const bf16x8*)(ftl + ab + 512);
#pragma unroll
    for (int nf = 0; nf < 4; ++nf) {
      acc[mf][nf] = __builtin_amdgcn_mfma_f32_16x16x32_bf16(ah0, bfr[nf][0], acc[mf][nf], 0, 0, 0);
      acc[mf][nf] = __builtin_amdgcn_mfma_f32_16x16x32_bf16(al0, bfr[nf][0], acc[mf][nf], 0, 0, 0);
      acc[mf][nf] = __builtin_amdgcn_mfma_f32_16x16x32_bf16(ah1, bfr[nf][1], acc[mf][nf], 0, 0, 0);
      acc[mf][nf] = __builtin_amdgcn_mfma_f32_16x16x32_bf16(al1, bfr[nf][1], acc[mf][nf], 0, 0, 0);
    }
  }

  float bs[4];
#pragma unroll
  for (int nf = 0; nf < 4; ++nf) bs[nf] = bias[n0 + nf * 16 + (l & 15)];

  if (MODE == 0) {
    float m = 0.0f;
#pragma unroll
    for (int mf = 0; mf < 4; ++mf)
#pragma unroll
      for (int nf = 0; nf < 4; ++nf)
#pragma unroll
        for (int j = 0; j < 4; ++j)
          m = fmaxf(m, fabsf(s2 * acc[mf][nf][j] + bs[nf]));
    m = wave_max(m);
    if ((tid & 63) == 0) wred[tid >> 6] = m;
    __syncthreads();
    if (tid == 0) {
      bmax[flat] = fmaxf(fmaxf(wred[0], wred[1]), fmaxf(wred[2], wred[3]));
    }
  } else {
    float sY = slots_f[3];
    float inv = 1.0f / sY;
#pragma unroll
    for (int mf = 0; mf < 4; ++mf) {
      int r0 = m0 + mf * 16 + (l >> 4) * 4;
#pragma unroll
      for (int nf = 0; nf < 4; ++nf) {
        int c = n0 + nf * 16 + (l & 15);
#pragma unroll
        for (int j = 0; j < 4; ++j) {
          float v = s2 * acc[mf][nf][j] + bs[nf];
          float q = fminf(fmaxf(rintf(v * inv), -128.0f), 127.0f) * sY;
          out[(size_t)(r0 + j) * NOUT + c] = fmaxf(q, 0.0f);
        }
      }
    }
  }
}

// ---------------------------------------------------------------------------
// Kernel 5: reduce 2048 block maxima -> sY scale in slots_f[3]
// ---------------------------------------------------------------------------
__global__ __launch_bounds__(256) void reduce_bmax(
    const float* __restrict__ bmax, float* __restrict__ slots_f) {
  __shared__ float wred[4];
  int tid = threadIdx.x;
  float m = 0.0f;
#pragma unroll
  for (int i = 0; i < 8; ++i) m = fmaxf(m, bmax[tid + i * 256]);
  m = wave_max(m);
  if ((tid & 63) == 0) wred[tid >> 6] = m;
  __syncthreads();
  if (tid == 0) {
    float mm = fmaxf(fmaxf(wred[0], wred[1]), fmaxf(wred[2], wred[3]));
    slots_f[3] = fmaxf(mm * (1.0f / 127.0f), 1e-8f);
  }
}

extern "C" void kernel_launch(void* const* d_in, const int* in_sizes, int n_in,
                              void* d_out, int out_size, void* d_ws,
                              size_t ws_size, hipStream_t stream) {
  (void)in_sizes; (void)n_in; (void)out_size; (void)ws_size;
  const float* x0 = (const float*)d_in[0];
  const float* x1 = (const float*)d_in[1];
  const float* f0 = (const float*)d_in[2];
  const float* f1 = (const float*)d_in[3];
  const float* f2 = (const float*)d_in[4];
  const float* bias = (const float*)d_in[5];
  float* out = (float*)d_out;

  char* ws = (char*)d_ws;
  float* slots_f = (float*)ws;  // [2]=s2 scale, [3]=sY scale
  float* pf2  = (float*)(ws + OFF_PF2);
  float* bmax = (float*)(ws + OFF_BMAX);
  unsigned short* fc2 = (unsigned short*)(ws + OFF_FC2);
  unsigned short* fth = (unsigned short*)(ws + OFF_FTH);
  unsigned short* ftl = (unsigned short*)(ws + OFF_FTL);

  absmax_f2<<<256, 256, 0, stream>>>(f2, pf2);
  prep_f2<<<256, 256, 0, stream>>>(f2, pf2, slots_f, fc2);
  stage1_fused<<<512, 256, 0, stream>>>(x0, x1, f0, f1, fth, ftl);
  stage2<0><<<2048, 256, 0, stream>>>(fth, ftl, fc2, bias, slots_f, bmax,
                                      nullptr);
  reduce_bmax<<<1, 256, 0, stream>>>(bmax, slots_f);
  stage2<1><<<2048, 256, 0, stream>>>(fth, ftl, fc2, bias, slots_f, nullptr,
                                      out);
}